// Round 5
// baseline (330.218 us; speedup 1.0000x reference)
//
#include <hip/hip_runtime.h>
#include <stdint.h>

#define B_  8
#define C_  384
#define N_  4096
#define NH_ 8
#define HD_ 48
#define CB_ (C_*N_)
#define KS2 768   // 2 x 384 (scaled-f16 hi/lo split of f32 weights)

typedef __attribute__((ext_vector_type(8))) short short8;
typedef __attribute__((ext_vector_type(8))) _Float16 half8;
typedef __attribute__((ext_vector_type(4))) float f32x4;

// all inputs are float32 (reference dtypes)
struct P5 { const float *w, *g, *be, *mu, *va; };
struct W4 { const float *w0, *w1, *w2, *w3; };

__device__ __forceinline__ float b2f(unsigned short u) {
    union { unsigned int i; float f; } c; c.i = ((unsigned int)u) << 16; return c.f;
}
__device__ __forceinline__ unsigned short f2b(float f) {
    union { float f; unsigned int i; } c; c.f = f;
    return (unsigned short)((c.i + 0x7FFFu + ((c.i >> 16) & 1u)) >> 16);
}
__device__ __forceinline__ unsigned short f2h(float f) {   // f32 -> f16 bits (RTE); exact for quantized vals
    union { _Float16 h; unsigned short u; } c; c.h = (_Float16)f; return c.u;
}
__device__ __forceinline__ float spikef(float f) {
    f = fminf(fmaxf(f, 0.0f), 4.0f);
    return rintf(f) * 0.25f;   // round-half-even == np.round
}
__device__ __forceinline__ void async16(const void* g, void* l) {
    __builtin_amdgcn_global_load_lds((const __attribute__((address_space(1))) void*)g,
                                     (__attribute__((address_space(3))) void*)l, 16, 0, 0);
}

// ---------------- Kp: scaled-f16 2-way split of the four f32 weight matrices ----------------
// wsp[mat][o][c']: c'<384: lo = f16((w-hi)*4096), c' in [384,768): hi = f16(w)
__global__ __launch_bounds__(256) void k_prep(W4 ws4, unsigned short* __restrict__ wsp) {
    int idx = blockIdx.x * 256 + threadIdx.x;          // 4*384*384 = 589824
    if (idx >= 589824) return;
    int mat = idx / 147456, rem = idx % 147456;
    int o = rem / 384, c = rem % 384;
    const float* W = (mat == 0) ? ws4.w0 : (mat == 1) ? ws4.w1 : (mat == 2) ? ws4.w2 : ws4.w3;
    float w = W[o * 384 + c];
    _Float16 hh = (fabsf(w) < 6.103515625e-05f) ? (_Float16)0 : (_Float16)w;  // keep hi normal (or 0)
    float r1 = w - (float)hh;                    // exact
    float s  = r1 * 4096.0f;                     // exact (pow2)
    union { _Float16 h; unsigned short u; } ch, cl;
    ch.h = hh; cl.h = (_Float16)s;
    unsigned short* row = wsp + (size_t)mat * 384 * KS2 + (size_t)o * KS2 + c;
    row[0] = cl.u; row[384] = ch.u;
}

// ---------------- K0: xs = spike(x) (f32 in), transposed to f16 [b][n][c] ----------------
__global__ __launch_bounds__(256) void k0_spike_T(const float* __restrict__ x,
                                                  unsigned short* __restrict__ xst) {
    int nt = blockIdx.x, ct = blockIdx.y, b = blockIdx.z;
    int t = threadIdx.x;
    __shared__ __attribute__((aligned(16))) unsigned short sm[64][68];
    int n0 = nt * 64, c0 = ct * 64;
    const float* xb = x + (size_t)b * CB_;
    #pragma unroll
    for (int i = 0; i < 4; ++i) {
        int c = (t >> 4) + 16 * i;
        int seg = t & 15;
        float4 d = *(const float4*)(xb + (size_t)(c0 + c) * N_ + n0 + seg * 4);
        unsigned short v[4];
        v[0] = f2h(spikef(d.x)); v[1] = f2h(spikef(d.y));
        v[2] = f2h(spikef(d.z)); v[3] = f2h(spikef(d.w));
        *(uint2*)&sm[c][seg * 4] = *(const uint2*)v;
    }
    __syncthreads();
    unsigned short* ob = xst + (size_t)b * CB_;
    #pragma unroll
    for (int i = 0; i < 2; ++i) {
        int flat = i * 256 + t;
        int n = flat >> 3, segc = flat & 7;
        unsigned short v[8];
        #pragma unroll
        for (int j = 0; j < 8; ++j) v[j] = sm[segc * 8 + j][n];
        *(uint4*)(ob + (size_t)(n0 + n) * C_ + c0 + segc * 8) = *(const uint4*)v;
    }
}

// ---------------- K1: fused q/k/v conv+BN+spike GEMM, merged hi/lo, XCD-swizzled ----------------
// 2304 blocks = 8 xcd * (32 ntile-b-pairs... ) : all 9 mt sharing an A tile land on ONE xcd
__global__ __launch_bounds__(256) void k1_qkv(const unsigned short* __restrict__ xst,
                                              const unsigned short* __restrict__ wsp,
                                              P5 pq, P5 pk, P5 pv,
                                              unsigned short* __restrict__ qs,
                                              unsigned short* __restrict__ ks,
                                              unsigned short* __restrict__ vs) {
    int gid = blockIdx.x;
    int xcd = gid & 7, idx = gid >> 3;        // idx in [0,288)
    int pairSlot = idx / 9, mt = idx - pairSlot * 9;
    int p = xcd * 32 + pairSlot;              // [0,256): ntile-b pair
    int ntile = p >> 3, b = p & 7;
    int mat = mt / 3;
    int orow0 = (mt % 3) * 128;
    int n0 = ntile * 128;
    int t = threadIdx.x, lane = t & 63, wvv = t >> 6;
    int wr = wvv >> 1, wc = wvv & 1;

    __shared__ __attribute__((aligned(16))) short lds[24576]; // A | B_lo | B_hi (8192 shorts each)
    P5 pp = (mat == 0) ? pq : (mat == 1 ? pk : pv);
    const unsigned short* abase = xst + (size_t)b * CB_;
    const unsigned short* wbase = wsp + (size_t)mat * 384 * KS2;

    f32x4 accH[4][4] = {}, accL[4][4] = {};
    for (int kk = 0; kk < 384; kk += 64) {
        #pragma unroll
        for (int j = 0; j < 4; ++j) {
            int row = wvv * 32 + j * 8 + (lane >> 3);
            int g = (lane & 7) ^ (row & 7);
            async16(abase + (size_t)(n0 + row) * C_ + kk + g * 8, lds + (wvv * 32 + j * 8) * 64);
        }
        #pragma unroll
        for (int j = 0; j < 4; ++j) {
            int row = wvv * 32 + j * 8 + (lane >> 3);
            int g = (lane & 7) ^ (row & 7);
            async16(wbase + (size_t)(orow0 + row) * KS2 + kk + g * 8, lds + 8192 + (wvv * 32 + j * 8) * 64);
        }
        #pragma unroll
        for (int j = 0; j < 4; ++j) {
            int row = wvv * 32 + j * 8 + (lane >> 3);
            int g = (lane & 7) ^ (row & 7);
            async16(wbase + (size_t)(orow0 + row) * KS2 + 384 + kk + g * 8, lds + 16384 + (wvv * 32 + j * 8) * 64);
        }
        __syncthreads();
        #pragma unroll
        for (int ksb = 0; ksb < 2; ++ksb) {
            half8 af[4], bl[4], bh[4];
            #pragma unroll
            for (int mi = 0; mi < 4; ++mi) {
                int row = wr * 64 + mi * 16 + (lane & 15);
                int s = (ksb * 4 + (lane >> 4)) ^ (row & 7);
                af[mi] = *(const half8*)&lds[row * 64 + s * 8];
            }
            #pragma unroll
            for (int ni = 0; ni < 4; ++ni) {
                int row = wc * 64 + ni * 16 + (lane & 15);
                int s = (ksb * 4 + (lane >> 4)) ^ (row & 7);
                bl[ni] = *(const half8*)&lds[8192 + row * 64 + s * 8];
                bh[ni] = *(const half8*)&lds[16384 + row * 64 + s * 8];
            }
            #pragma unroll
            for (int mi = 0; mi < 4; ++mi)
                #pragma unroll
                for (int ni = 0; ni < 4; ++ni) {
                    accL[mi][ni] = __builtin_amdgcn_mfma_f32_16x16x32_f16(af[mi], bl[ni], accL[mi][ni], 0, 0, 0);
                    accH[mi][ni] = __builtin_amdgcn_mfma_f32_16x16x32_f16(af[mi], bh[ni], accH[mi][ni], 0, 0, 0);
                }
        }
        __syncthreads();
    }

    float s_bn[4], t_bn[4];
    #pragma unroll
    for (int ni = 0; ni < 4; ++ni) {
        int o = orow0 + wc * 64 + ni * 16 + (lane & 15);
        float g = pp.g[o], be = pp.be[o], mu = pp.mu[o], va = pp.va[o];
        float s = g / sqrtf(va + 1e-5f);
        s_bn[ni] = s; t_bn[ni] = be - mu * s;
    }
    unsigned short* esm = (unsigned short*)lds;

    if (mat != 0) {  // k,v -> [b][c][n] (bf16 for K2/K3)
        #pragma unroll
        for (int mi = 0; mi < 4; ++mi)
            #pragma unroll
            for (int ni = 0; ni < 4; ++ni) {
                int ol = wc * 64 + ni * 16 + (lane & 15);
                int nb = wr * 64 + mi * 16 + (lane >> 4) * 4;
                unsigned short vv[4];
                #pragma unroll
                for (int r = 0; r < 4; ++r) {
                    float v = accH[mi][ni][r] + accL[mi][ni][r] * 0.000244140625f;
                    vv[r] = f2b(spikef(v * s_bn[ni] + t_bn[ni]));
                }
                *(uint2*)&esm[ol * 136 + nb] = *(const uint2*)vv;
            }
        __syncthreads();
        unsigned short* dst = ((mat == 1) ? ks : vs) + (size_t)b * CB_;
        #pragma unroll
        for (int i = 0; i < 8; ++i) {
            int o = (t >> 4) + 16 * i;
            int seg = t & 15;
            uint4 d = *(const uint4*)&esm[o * 136 + seg * 8];
            *(uint4*)(dst + (size_t)(orow0 + o) * N_ + n0 + seg * 8) = d;
        }
    } else {        // q -> [b][n][c] (bf16 for K3)
        #pragma unroll
        for (int mi = 0; mi < 4; ++mi)
            #pragma unroll
            for (int ni = 0; ni < 4; ++ni) {
                int ol = wc * 64 + ni * 16 + (lane & 15);
                int nb = wr * 64 + mi * 16 + (lane >> 4) * 4;
                #pragma unroll
                for (int r = 0; r < 4; ++r) {
                    float v = accH[mi][ni][r] + accL[mi][ni][r] * 0.000244140625f;
                    esm[(nb + r) * 136 + ol] = f2b(spikef(v * s_bn[ni] + t_bn[ni]));
                }
            }
        __syncthreads();
        #pragma unroll
        for (int i = 0; i < 8; ++i) {
            int n = (t >> 4) + 16 * i;
            int seg = t & 15;
            uint4 d = *(const uint4*)&esm[n * 136 + seg * 8];
            *(uint4*)(qs + ((size_t)b * N_ + n0 + n) * C_ + orow0 + seg * 8) = d;
        }
    }
}

// ---------------- K2: kv = k^T v per (b,h), split-K over 16 chunks ----------------
__global__ __launch_bounds__(256) void k2_kv(const unsigned short* __restrict__ ks,
                                             const unsigned short* __restrict__ vs,
                                             float* __restrict__ kvf) {
    int id = blockIdx.x;                 // 1024 = 64 bh * 16 chunks
    int b = id >> 7, h = (id >> 4) & 7, ck = id & 15;
    int t = threadIdx.x, lane = t & 63, w = t >> 6;
    const unsigned short* kb = ks + (size_t)b * CB_ + h * HD_ * N_;
    const unsigned short* vb = vs + (size_t)b * CB_ + h * HD_ * N_;
    int kbase = ck * 256 + w * 64;

    f32x4 acc[3][3] = {};
    #pragma unroll
    for (int kk = 0; kk < 64; kk += 32) {
        int n = kbase + kk + (lane >> 4) * 8;
        short8 af[3], bfr[3];
        #pragma unroll
        for (int di = 0; di < 3; ++di)
            af[di] = *(const short8*)(kb + (size_t)((lane & 15) + 16 * di) * N_ + n);
        #pragma unroll
        for (int ei = 0; ei < 3; ++ei)
            bfr[ei] = *(const short8*)(vb + (size_t)((lane & 15) + 16 * ei) * N_ + n);
        #pragma unroll
        for (int di = 0; di < 3; ++di)
            #pragma unroll
            for (int ei = 0; ei < 3; ++ei)
                acc[di][ei] = __builtin_amdgcn_mfma_f32_16x16x32_bf16(af[di], bfr[ei], acc[di][ei], 0, 0, 0);
    }
    __shared__ float red[4][48][48];
    #pragma unroll
    for (int di = 0; di < 3; ++di)
        #pragma unroll
        for (int ei = 0; ei < 3; ++ei) {
            int d0 = di * 16 + (lane >> 4) * 4;
            int e = ei * 16 + (lane & 15);
            #pragma unroll
            for (int r = 0; r < 4; ++r) red[w][d0 + r][e] = acc[di][ei][r];
        }
    __syncthreads();
    for (int i = t; i < 2304; i += 256) {
        int e = i / 48, d = i % 48;
        float sum = red[0][d][e] + red[1][d][e] + red[2][d][e] + red[3][d][e];
        atomicAdd(&kvf[(b * NH_ + h) * 2304 + e * 48 + d], sum);  // [e][d]; exact (1/16 multiples)
    }
}

// ---------------- K2b: kv fp32 -> bf16 hi/lo (exact), d padded 48->64 ----------------
__global__ __launch_bounds__(256) void k2b_split(const float* __restrict__ kvf,
                                                 unsigned short* __restrict__ hi,
                                                 unsigned short* __restrict__ lo) {
    int i = blockIdx.x * 256 + threadIdx.x;      // 64*48*64 = 196608
    if (i >= 64 * 48 * 64) return;
    int d = i & 63; int rest = i >> 6;
    unsigned short h16 = 0, l16 = 0;
    if (d < 48) {
        float v = kvf[rest * 48 + d];
        h16 = f2b(v);
        l16 = f2b(v - b2f(h16));                 // hi+lo == v exactly (<=16-bit fixed point)
    }
    hi[i] = h16; lo[i] = l16;
}

// ---------------- K3: attn = q @ kv * s2, spike -> a_s f16 [b][n][c], LDS-coalesced stores ----------------
__global__ __launch_bounds__(256) void k3_attn(const unsigned short* __restrict__ qs,
                                               const unsigned short* __restrict__ hi,
                                               const unsigned short* __restrict__ lo,
                                               unsigned short* __restrict__ as_) {
    int id = blockIdx.x;                          // 512 = 8 b * 64 ntiles
    int b = id >> 6, nt = id & 63;
    int t = threadIdx.x, lane = t & 63, w = t >> 6;
    int nb0 = nt * 64;
    int n0 = nb0 + w * 16;
    const unsigned short* qb = qs + ((size_t)b * N_ + n0) * C_;
    const float S2 = 0.28867513459481287f;        // f32(2/sqrt(48)) as in reference
    __shared__ __attribute__((aligned(16))) unsigned short sm[64][392];

    for (int h = 0; h < NH_; ++h) {
        f32x4 acc[3] = {};
        #pragma unroll
        for (int ksb = 0; ksb < 2; ++ksb) {
            int koff = h * HD_ + ksb * 32 + (lane >> 4) * 8;  // tail overread hits finite data; B pad=0
            short8 a = *(const short8*)(qb + (size_t)(lane & 15) * C_ + koff);
            #pragma unroll
            for (int ei = 0; ei < 3; ++ei) {
                int e = ei * 16 + (lane & 15);
                size_t boff = ((size_t)(b * NH_ + h) * HD_ + e) * 64 + ksb * 32 + (lane >> 4) * 8;
                short8 bh = *(const short8*)(hi + boff);
                short8 bl = *(const short8*)(lo + boff);
                acc[ei] = __builtin_amdgcn_mfma_f32_16x16x32_bf16(a, bh, acc[ei], 0, 0, 0);
                acc[ei] = __builtin_amdgcn_mfma_f32_16x16x32_bf16(a, bl, acc[ei], 0, 0, 0);
            }
        }
        #pragma unroll
        for (int ei = 0; ei < 3; ++ei) {
            int e = ei * 16 + (lane & 15);
            #pragma unroll
            for (int r = 0; r < 4; ++r)
                sm[w * 16 + (lane >> 4) * 4 + r][h * HD_ + e] = f2h(spikef(acc[ei][r] * S2));
        }
    }
    __syncthreads();
    unsigned short* ob = as_ + ((size_t)b * N_ + nb0) * C_;
    #pragma unroll
    for (int i = 0; i < 12; ++i) {
        int f = i * 256 + t;
        int row = f / 48, seg = f % 48;
        uint4 d = *(const uint4*)&sm[row][seg * 8];
        *(uint4*)(ob + (size_t)row * C_ + seg * 8) = d;
    }
}

// ---------------- K4: out = BN(P @ a_s) -> f32 [b][c][n], merged hi/lo, XCD-swizzled ----------------
__global__ __launch_bounds__(256) void k4_pconv(const unsigned short* __restrict__ as_,
                                                const unsigned short* __restrict__ wsp,
                                                P5 pp,
                                                float* __restrict__ out) {
    int gid = blockIdx.x;                      // 768 = 8 xcd * 96
    int xcd = gid & 7, idx = gid >> 3;         // idx in [0,96)
    int pairSlot = idx / 3, mt = idx - pairSlot * 3;
    int p = xcd * 32 + pairSlot;               // [0,256)
    int ntile = p >> 3, b = p & 7;
    int orow0 = mt * 128;
    int n0 = ntile * 128;
    int t = threadIdx.x, lane = t & 63, wvv = t >> 6;
    int wr = wvv >> 1, wc = wvv & 1;

    __shared__ __attribute__((aligned(16))) short lds[24576];
    const unsigned short* abase = as_ + (size_t)b * CB_;
    const unsigned short* wbase = wsp + (size_t)3 * 384 * KS2;   // p-matrix split

    f32x4 accH[4][4] = {}, accL[4][4] = {};
    for (int kk = 0; kk < 384; kk += 64) {
        #pragma unroll
        for (int j = 0; j < 4; ++j) {
            int row = wvv * 32 + j * 8 + (lane >> 3);
            int g = (lane & 7) ^ (row & 7);
            async16(abase + (size_t)(n0 + row) * C_ + kk + g * 8, lds + (wvv * 32 + j * 8) * 64);
        }
        #pragma unroll
        for (int j = 0; j < 4; ++j) {
            int row = wvv * 32 + j * 8 + (lane >> 3);
            int g = (lane & 7) ^ (row & 7);
            async16(wbase + (size_t)(orow0 + row) * KS2 + kk + g * 8, lds + 8192 + (wvv * 32 + j * 8) * 64);
        }
        #pragma unroll
        for (int j = 0; j < 4; ++j) {
            int row = wvv * 32 + j * 8 + (lane >> 3);
            int g = (lane & 7) ^ (row & 7);
            async16(wbase + (size_t)(orow0 + row) * KS2 + 384 + kk + g * 8, lds + 16384 + (wvv * 32 + j * 8) * 64);
        }
        __syncthreads();
        #pragma unroll
        for (int ksb = 0; ksb < 2; ++ksb) {
            half8 af[4], bl[4], bh[4];
            #pragma unroll
            for (int mi = 0; mi < 4; ++mi) {
                int row = wr * 64 + mi * 16 + (lane & 15);
                int s = (ksb * 4 + (lane >> 4)) ^ (row & 7);
                af[mi] = *(const half8*)&lds[row * 64 + s * 8];
            }
            #pragma unroll
            for (int ni = 0; ni < 4; ++ni) {
                int row = wc * 64 + ni * 16 + (lane & 15);
                int s = (ksb * 4 + (lane >> 4)) ^ (row & 7);
                bl[ni] = *(const half8*)&lds[8192 + row * 64 + s * 8];
                bh[ni] = *(const half8*)&lds[16384 + row * 64 + s * 8];
            }
            #pragma unroll
            for (int mi = 0; mi < 4; ++mi)
                #pragma unroll
                for (int ni = 0; ni < 4; ++ni) {
                    accL[mi][ni] = __builtin_amdgcn_mfma_f32_16x16x32_f16(af[mi], bl[ni], accL[mi][ni], 0, 0, 0);
                    accH[mi][ni] = __builtin_amdgcn_mfma_f32_16x16x32_f16(af[mi], bh[ni], accH[mi][ni], 0, 0, 0);
                }
        }
        __syncthreads();
    }

    float s_bn[4], t_bn[4];
    #pragma unroll
    for (int ni = 0; ni < 4; ++ni) {
        int o = orow0 + wc * 64 + ni * 16 + (lane & 15);
        float g = pp.g[o], be = pp.be[o], mu = pp.mu[o], va = pp.va[o];
        float s = g / sqrtf(va + 1e-5f);
        s_bn[ni] = s; t_bn[ni] = be - mu * s;
    }
    #pragma unroll
    for (int mi = 0; mi < 4; ++mi)
        #pragma unroll
        for (int ni = 0; ni < 4; ++ni) {
            int o = orow0 + wc * 64 + ni * 16 + (lane & 15);
            int n = n0 + wr * 64 + mi * 16 + (lane >> 4) * 4;
            f32x4 vv;
            #pragma unroll
            for (int r = 0; r < 4; ++r) {
                float v = accH[mi][ni][r] + accL[mi][ni][r] * 0.000244140625f;
                vv[r] = v * s_bn[ni] + t_bn[ni];
            }
            *(f32x4*)(out + ((size_t)b * C_ + o) * N_ + n) = vv;
        }
}

extern "C" void kernel_launch(void* const* d_in, const int* in_sizes, int n_in,
                              void* d_out, int out_size, void* d_ws, size_t ws_size,
                              hipStream_t stream) {
    P5 pq { (const float*)d_in[1],  (const float*)d_in[2],  (const float*)d_in[3],
            (const float*)d_in[4],  (const float*)d_in[5] };
    P5 pk { (const float*)d_in[6],  (const float*)d_in[7],  (const float*)d_in[8],
            (const float*)d_in[9],  (const float*)d_in[10] };
    P5 pv { (const float*)d_in[11], (const float*)d_in[12], (const float*)d_in[13],
            (const float*)d_in[14], (const float*)d_in[15] };
    P5 pp { (const float*)d_in[16], (const float*)d_in[17], (const float*)d_in[18],
            (const float*)d_in[19], (const float*)d_in[20] };
    W4 w4 { pq.w, pk.w, pv.w, pp.w };

    char* ws = (char*)d_ws;
    const size_t S = (size_t)B_ * C_ * N_ * 2;          // 25165824 B per 16-bit tensor
    unsigned short* xst = (unsigned short*)ws;          // f16; aliased with a_s (disjoint lifetimes)
    unsigned short* qs  = (unsigned short*)(ws + S);
    unsigned short* ks  = (unsigned short*)(ws + 2 * S + 256);
    unsigned short* vs  = (unsigned short*)(ws + 3 * S + 512);
    float*          kvf = (float*)(ws + 4 * S + 768);                          // 589824 B
    unsigned short* hi  = (unsigned short*)(ws + 4 * S + 768 + 589824);        // 393216 B
    unsigned short* lo  = (unsigned short*)(ws + 4 * S + 768 + 589824 + 393216);
    unsigned short* wsp = (unsigned short*)(ws + 4 * S + 768 + 589824 + 2 * 393216); // 2359296 B
    unsigned short* as_ = xst;

    hipMemsetAsync(kvf, 0, 589824, stream);
    k_prep<<<2304, 256, 0, stream>>>(w4, wsp);
    k0_spike_T<<<dim3(64, 6, 8), 256, 0, stream>>>((const float*)d_in[0], xst);
    k1_qkv<<<2304, 256, 0, stream>>>(xst, wsp, pq, pk, pv, qs, ks, vs);
    k2_kv<<<1024, 256, 0, stream>>>(ks, vs, kvf);
    k2b_split<<<768, 256, 0, stream>>>(kvf, hi, lo);
    k3_attn<<<512, 256, 0, stream>>>(qs, hi, lo, as_);
    k4_pconv<<<768, 256, 0, stream>>>(as_, wsp, pp, (float*)d_out);
}

// Round 6
// 271.999 us; speedup vs baseline: 1.2140x; 1.2140x over previous
//
#include <hip/hip_runtime.h>
#include <stdint.h>

#define B_  8
#define C_  384
#define N_  4096
#define NH_ 8
#define HD_ 48
#define CB_ (C_*N_)
#define KS2 768   // 2 x 384 (scaled-f16 hi/lo split of f32 weights)

typedef __attribute__((ext_vector_type(8))) short short8;
typedef __attribute__((ext_vector_type(8))) _Float16 half8;
typedef __attribute__((ext_vector_type(4))) float f32x4;

// all inputs are float32 (reference dtypes)
struct P5 { const float *w, *g, *be, *mu, *va; };
struct W4 { const float *w0, *w1, *w2, *w3; };

__device__ __forceinline__ float b2f(unsigned short u) {
    union { unsigned int i; float f; } c; c.i = ((unsigned int)u) << 16; return c.f;
}
__device__ __forceinline__ unsigned short f2b(float f) {
    union { float f; unsigned int i; } c; c.f = f;
    return (unsigned short)((c.i + 0x7FFFu + ((c.i >> 16) & 1u)) >> 16);
}
__device__ __forceinline__ unsigned short f2h(float f) {   // f32 -> f16 bits (RTE); exact for quantized vals
    union { _Float16 h; unsigned short u; } c; c.h = (_Float16)f; return c.u;
}
__device__ __forceinline__ float spikef(float f) {
    f = fminf(fmaxf(f, 0.0f), 4.0f);
    return rintf(f) * 0.25f;   // round-half-even == np.round
}
__device__ __forceinline__ void async16(const void* g, void* l) {
    __builtin_amdgcn_global_load_lds((const __attribute__((address_space(1))) void*)g,
                                     (__attribute__((address_space(3))) void*)l, 16, 0, 0);
}

// ---------------- Kp: scaled-f16 2-way split of the four f32 weight matrices ----------------
// wsp[mat][o][c']: c'<384: lo = f16((w-hi)*4096), c' in [384,768): hi = f16(w)
__global__ __launch_bounds__(256) void k_prep(W4 ws4, unsigned short* __restrict__ wsp) {
    int idx = blockIdx.x * 256 + threadIdx.x;          // 4*384*384 = 589824
    if (idx >= 589824) return;
    int mat = idx / 147456, rem = idx % 147456;
    int o = rem / 384, c = rem % 384;
    const float* W = (mat == 0) ? ws4.w0 : (mat == 1) ? ws4.w1 : (mat == 2) ? ws4.w2 : ws4.w3;
    float w = W[o * 384 + c];
    _Float16 hh = (fabsf(w) < 6.103515625e-05f) ? (_Float16)0 : (_Float16)w;  // keep hi normal (or 0)
    float r1 = w - (float)hh;                    // exact
    float s  = r1 * 4096.0f;                     // exact (pow2)
    union { _Float16 h; unsigned short u; } ch, cl;
    ch.h = hh; cl.h = (_Float16)s;
    unsigned short* row = wsp + (size_t)mat * 384 * KS2 + (size_t)o * KS2 + c;
    row[0] = cl.u; row[384] = ch.u;
}

// ---------------- K0: xs = spike(x) (f32 in), transposed to f16 [b][n][c] ----------------
__global__ __launch_bounds__(256) void k0_spike_T(const float* __restrict__ x,
                                                  unsigned short* __restrict__ xst) {
    int nt = blockIdx.x, ct = blockIdx.y, b = blockIdx.z;
    int t = threadIdx.x;
    __shared__ __attribute__((aligned(16))) unsigned short sm[64][68];
    int n0 = nt * 64, c0 = ct * 64;
    const float* xb = x + (size_t)b * CB_;
    #pragma unroll
    for (int i = 0; i < 4; ++i) {
        int c = (t >> 4) + 16 * i;
        int seg = t & 15;
        float4 d = *(const float4*)(xb + (size_t)(c0 + c) * N_ + n0 + seg * 4);
        unsigned short v[4];
        v[0] = f2h(spikef(d.x)); v[1] = f2h(spikef(d.y));
        v[2] = f2h(spikef(d.z)); v[3] = f2h(spikef(d.w));
        *(uint2*)&sm[c][seg * 4] = *(const uint2*)v;
    }
    __syncthreads();
    unsigned short* ob = xst + (size_t)b * CB_;
    #pragma unroll
    for (int i = 0; i < 2; ++i) {
        int flat = i * 256 + t;
        int n = flat >> 3, segc = flat & 7;
        unsigned short v[8];
        #pragma unroll
        for (int j = 0; j < 8; ++j) v[j] = sm[segc * 8 + j][n];
        *(uint4*)(ob + (size_t)(n0 + n) * C_ + c0 + segc * 8) = *(const uint4*)v;
    }
}

// ---------------- K1: fused q/k/v conv+BN+spike GEMM (2-pass scaled-f16), XCD-swizzled ----------------
// 2304 blocks; the 9 mt-blocks sharing one A tile land on one XCD (gid % 8 = XCD round-robin)
__global__ __launch_bounds__(256) void k1_qkv(const unsigned short* __restrict__ xst,
                                              const unsigned short* __restrict__ wsp,
                                              P5 pq, P5 pk, P5 pv,
                                              unsigned short* __restrict__ qs,
                                              unsigned short* __restrict__ ks,
                                              unsigned short* __restrict__ vs) {
    int gid = blockIdx.x;
    int xcd = gid & 7, idx = gid >> 3;        // idx in [0,288)
    int pairSlot = idx / 9, mt = idx - pairSlot * 9;
    int p = xcd * 32 + pairSlot;              // [0,256): ntile-b pair
    int ntile = p >> 3, b = p & 7;
    int mat = mt / 3;
    int orow0 = (mt % 3) * 128;
    int n0 = ntile * 128;
    int t = threadIdx.x, lane = t & 63, wvv = t >> 6;
    int wr = wvv >> 1, wc = wvv & 1;

    __shared__ __attribute__((aligned(16))) short lds[17408]; // A | B (8192 shorts each); epilogue reuse
    P5 pp = (mat == 0) ? pq : (mat == 1 ? pk : pv);
    const unsigned short* abase = xst + (size_t)b * CB_;
    const unsigned short* wbase = wsp + (size_t)mat * 384 * KS2;

    f32x4 acc[4][4] = {};
    for (int kk = 0; kk < KS2; kk += 64) {
        if (kk == 384) {        // finished lo pass: scale partial sums by 2^-12
            #pragma unroll
            for (int mi = 0; mi < 4; ++mi)
                #pragma unroll
                for (int ni = 0; ni < 4; ++ni)
                    acc[mi][ni] = acc[mi][ni] * 0.000244140625f;
        }
        int ck = (kk >= 384) ? kk - 384 : kk;   // A repeats per pass (L2-hot after swizzle)
        #pragma unroll
        for (int j = 0; j < 4; ++j) {
            int row = wvv * 32 + j * 8 + (lane >> 3);
            int g = (lane & 7) ^ (row & 7);
            async16(abase + (size_t)(n0 + row) * C_ + ck + g * 8, lds + (wvv * 32 + j * 8) * 64);
        }
        #pragma unroll
        for (int j = 0; j < 4; ++j) {
            int row = wvv * 32 + j * 8 + (lane >> 3);
            int g = (lane & 7) ^ (row & 7);
            async16(wbase + (size_t)(orow0 + row) * KS2 + kk + g * 8, lds + 8192 + (wvv * 32 + j * 8) * 64);
        }
        __syncthreads();
        #pragma unroll
        for (int ksb = 0; ksb < 2; ++ksb) {
            half8 af[4], bfr[4];
            #pragma unroll
            for (int mi = 0; mi < 4; ++mi) {
                int row = wr * 64 + mi * 16 + (lane & 15);
                int s = (ksb * 4 + (lane >> 4)) ^ (row & 7);
                af[mi] = *(const half8*)&lds[row * 64 + s * 8];
            }
            #pragma unroll
            for (int ni = 0; ni < 4; ++ni) {
                int row = wc * 64 + ni * 16 + (lane & 15);
                int s = (ksb * 4 + (lane >> 4)) ^ (row & 7);
                bfr[ni] = *(const half8*)&lds[8192 + row * 64 + s * 8];
            }
            #pragma unroll
            for (int mi = 0; mi < 4; ++mi)
                #pragma unroll
                for (int ni = 0; ni < 4; ++ni)
                    acc[mi][ni] = __builtin_amdgcn_mfma_f32_16x16x32_f16(af[mi], bfr[ni], acc[mi][ni], 0, 0, 0);
        }
        __syncthreads();
    }

    float s_bn[4], t_bn[4];
    #pragma unroll
    for (int ni = 0; ni < 4; ++ni) {
        int o = orow0 + wc * 64 + ni * 16 + (lane & 15);
        float g = pp.g[o], be = pp.be[o], mu = pp.mu[o], va = pp.va[o];
        float s = g / sqrtf(va + 1e-5f);
        s_bn[ni] = s; t_bn[ni] = be - mu * s;
    }
    unsigned short* esm = (unsigned short*)lds;

    if (mat != 0) {  // k,v -> [b][c][n] (bf16 for K2/K3)
        #pragma unroll
        for (int mi = 0; mi < 4; ++mi)
            #pragma unroll
            for (int ni = 0; ni < 4; ++ni) {
                int ol = wc * 64 + ni * 16 + (lane & 15);
                int nb = wr * 64 + mi * 16 + (lane >> 4) * 4;
                unsigned short vv[4];
                #pragma unroll
                for (int r = 0; r < 4; ++r)
                    vv[r] = f2b(spikef(acc[mi][ni][r] * s_bn[ni] + t_bn[ni]));
                *(uint2*)&esm[ol * 136 + nb] = *(const uint2*)vv;
            }
        __syncthreads();
        unsigned short* dst = ((mat == 1) ? ks : vs) + (size_t)b * CB_;
        #pragma unroll
        for (int i = 0; i < 8; ++i) {
            int o = (t >> 4) + 16 * i;
            int seg = t & 15;
            uint4 d = *(const uint4*)&esm[o * 136 + seg * 8];
            *(uint4*)(dst + (size_t)(orow0 + o) * N_ + n0 + seg * 8) = d;
        }
    } else {        // q -> [b][n][c] (bf16 for K3)
        #pragma unroll
        for (int mi = 0; mi < 4; ++mi)
            #pragma unroll
            for (int ni = 0; ni < 4; ++ni) {
                int ol = wc * 64 + ni * 16 + (lane & 15);
                int nb = wr * 64 + mi * 16 + (lane >> 4) * 4;
                #pragma unroll
                for (int r = 0; r < 4; ++r)
                    esm[(nb + r) * 136 + ol] = f2b(spikef(acc[mi][ni][r] * s_bn[ni] + t_bn[ni]));
            }
        __syncthreads();
        #pragma unroll
        for (int i = 0; i < 8; ++i) {
            int n = (t >> 4) + 16 * i;
            int seg = t & 15;
            uint4 d = *(const uint4*)&esm[n * 136 + seg * 8];
            *(uint4*)(qs + ((size_t)b * N_ + n0 + n) * C_ + orow0 + seg * 8) = d;
        }
    }
}

// ---------------- K2: kv = k^T v per (b,h), split-K over 16 chunks ----------------
__global__ __launch_bounds__(256) void k2_kv(const unsigned short* __restrict__ ks,
                                             const unsigned short* __restrict__ vs,
                                             float* __restrict__ kvf) {
    int id = blockIdx.x;                 // 1024 = 64 bh * 16 chunks
    int b = id >> 7, h = (id >> 4) & 7, ck = id & 15;
    int t = threadIdx.x, lane = t & 63, w = t >> 6;
    const unsigned short* kb = ks + (size_t)b * CB_ + h * HD_ * N_;
    const unsigned short* vb = vs + (size_t)b * CB_ + h * HD_ * N_;
    int kbase = ck * 256 + w * 64;

    f32x4 acc[3][3] = {};
    #pragma unroll
    for (int kk = 0; kk < 64; kk += 32) {
        int n = kbase + kk + (lane >> 4) * 8;
        short8 af[3], bfr[3];
        #pragma unroll
        for (int di = 0; di < 3; ++di)
            af[di] = *(const short8*)(kb + (size_t)((lane & 15) + 16 * di) * N_ + n);
        #pragma unroll
        for (int ei = 0; ei < 3; ++ei)
            bfr[ei] = *(const short8*)(vb + (size_t)((lane & 15) + 16 * ei) * N_ + n);
        #pragma unroll
        for (int di = 0; di < 3; ++di)
            #pragma unroll
            for (int ei = 0; ei < 3; ++ei)
                acc[di][ei] = __builtin_amdgcn_mfma_f32_16x16x32_bf16(af[di], bfr[ei], acc[di][ei], 0, 0, 0);
    }
    __shared__ float red[4][48][48];
    #pragma unroll
    for (int di = 0; di < 3; ++di)
        #pragma unroll
        for (int ei = 0; ei < 3; ++ei) {
            int d0 = di * 16 + (lane >> 4) * 4;
            int e = ei * 16 + (lane & 15);
            #pragma unroll
            for (int r = 0; r < 4; ++r) red[w][d0 + r][e] = acc[di][ei][r];
        }
    __syncthreads();
    for (int i = t; i < 2304; i += 256) {
        int e = i / 48, d = i % 48;
        float sum = red[0][d][e] + red[1][d][e] + red[2][d][e] + red[3][d][e];
        atomicAdd(&kvf[(b * NH_ + h) * 2304 + e * 48 + d], sum);  // [e][d]; exact (1/16 multiples)
    }
}

// ---------------- K2b: kv fp32 -> bf16 hi/lo (exact), d padded 48->64 ----------------
__global__ __launch_bounds__(256) void k2b_split(const float* __restrict__ kvf,
                                                 unsigned short* __restrict__ hi,
                                                 unsigned short* __restrict__ lo) {
    int i = blockIdx.x * 256 + threadIdx.x;      // 64*48*64 = 196608
    if (i >= 64 * 48 * 64) return;
    int d = i & 63; int rest = i >> 6;
    unsigned short h16 = 0, l16 = 0;
    if (d < 48) {
        float v = kvf[rest * 48 + d];
        h16 = f2b(v);
        l16 = f2b(v - b2f(h16));                 // hi+lo == v exactly (<=16-bit fixed point)
    }
    hi[i] = h16; lo[i] = l16;
}

// ---------------- K3: attn = q @ kv * s2, spike -> a_s f16 [b][n][c], LDS-coalesced stores ----------------
__global__ __launch_bounds__(256) void k3_attn(const unsigned short* __restrict__ qs,
                                               const unsigned short* __restrict__ hi,
                                               const unsigned short* __restrict__ lo,
                                               unsigned short* __restrict__ as_) {
    int id = blockIdx.x;                          // 512 = 8 b * 64 ntiles
    int b = id >> 6, nt = id & 63;
    int t = threadIdx.x, lane = t & 63, w = t >> 6;
    int nb0 = nt * 64;
    int n0 = nb0 + w * 16;
    const unsigned short* qb = qs + ((size_t)b * N_ + n0) * C_;
    const float S2 = 0.28867513459481287f;        // f32(2/sqrt(48)) as in reference
    __shared__ __attribute__((aligned(16))) unsigned short sm[64][392];

    for (int h = 0; h < NH_; ++h) {
        f32x4 acc[3] = {};
        #pragma unroll
        for (int ksb = 0; ksb < 2; ++ksb) {
            int koff = h * HD_ + ksb * 32 + (lane >> 4) * 8;  // tail overread hits finite data; B pad=0
            short8 a = *(const short8*)(qb + (size_t)(lane & 15) * C_ + koff);
            #pragma unroll
            for (int ei = 0; ei < 3; ++ei) {
                int e = ei * 16 + (lane & 15);
                size_t boff = ((size_t)(b * NH_ + h) * HD_ + e) * 64 + ksb * 32 + (lane >> 4) * 8;
                short8 bh = *(const short8*)(hi + boff);
                short8 bl = *(const short8*)(lo + boff);
                acc[ei] = __builtin_amdgcn_mfma_f32_16x16x32_bf16(a, bh, acc[ei], 0, 0, 0);
                acc[ei] = __builtin_amdgcn_mfma_f32_16x16x32_bf16(a, bl, acc[ei], 0, 0, 0);
            }
        }
        #pragma unroll
        for (int ei = 0; ei < 3; ++ei) {
            int e = ei * 16 + (lane & 15);
            #pragma unroll
            for (int r = 0; r < 4; ++r)
                sm[w * 16 + (lane >> 4) * 4 + r][h * HD_ + e] = f2h(spikef(acc[ei][r] * S2));
        }
    }
    __syncthreads();
    unsigned short* ob = as_ + ((size_t)b * N_ + nb0) * C_;
    #pragma unroll
    for (int i = 0; i < 12; ++i) {
        int f = i * 256 + t;
        int row = f / 48, seg = f % 48;
        uint4 d = *(const uint4*)&sm[row][seg * 8];
        *(uint4*)(ob + (size_t)row * C_ + seg * 8) = d;
    }
}

// ---------------- K4: out = BN(P @ a_s) -> f32 [b][c][n] (2-pass scaled-f16), XCD-swizzled ----------------
__global__ __launch_bounds__(256) void k4_pconv(const unsigned short* __restrict__ as_,
                                                const unsigned short* __restrict__ wsp,
                                                P5 pp,
                                                float* __restrict__ out) {
    int gid = blockIdx.x;                      // 768 = 8 xcd * 96
    int xcd = gid & 7, idx = gid >> 3;         // idx in [0,96)
    int pairSlot = idx / 3, mt = idx - pairSlot * 3;
    int p = xcd * 32 + pairSlot;               // [0,256)
    int ntile = p >> 3, b = p & 7;
    int orow0 = mt * 128;
    int n0 = ntile * 128;
    int t = threadIdx.x, lane = t & 63, wvv = t >> 6;
    int wr = wvv >> 1, wc = wvv & 1;

    __shared__ __attribute__((aligned(16))) short lds[16384];
    const unsigned short* abase = as_ + (size_t)b * CB_;
    const unsigned short* wbase = wsp + (size_t)3 * 384 * KS2;   // p-matrix split

    f32x4 acc[4][4] = {};
    for (int kk = 0; kk < KS2; kk += 64) {
        if (kk == 384) {
            #pragma unroll
            for (int mi = 0; mi < 4; ++mi)
                #pragma unroll
                for (int ni = 0; ni < 4; ++ni)
                    acc[mi][ni] = acc[mi][ni] * 0.000244140625f;
        }
        int ck = (kk >= 384) ? kk - 384 : kk;
        #pragma unroll
        for (int j = 0; j < 4; ++j) {
            int row = wvv * 32 + j * 8 + (lane >> 3);
            int g = (lane & 7) ^ (row & 7);
            async16(abase + (size_t)(n0 + row) * C_ + ck + g * 8, lds + (wvv * 32 + j * 8) * 64);
        }
        #pragma unroll
        for (int j = 0; j < 4; ++j) {
            int row = wvv * 32 + j * 8 + (lane >> 3);
            int g = (lane & 7) ^ (row & 7);
            async16(wbase + (size_t)(orow0 + row) * KS2 + kk + g * 8, lds + 8192 + (wvv * 32 + j * 8) * 64);
        }
        __syncthreads();
        #pragma unroll
        for (int ksb = 0; ksb < 2; ++ksb) {
            half8 af[4], bfr[4];
            #pragma unroll
            for (int mi = 0; mi < 4; ++mi) {
                int row = wr * 64 + mi * 16 + (lane & 15);
                int s = (ksb * 4 + (lane >> 4)) ^ (row & 7);
                af[mi] = *(const half8*)&lds[row * 64 + s * 8];
            }
            #pragma unroll
            for (int ni = 0; ni < 4; ++ni) {
                int row = wc * 64 + ni * 16 + (lane & 15);
                int s = (ksb * 4 + (lane >> 4)) ^ (row & 7);
                bfr[ni] = *(const half8*)&lds[8192 + row * 64 + s * 8];
            }
            #pragma unroll
            for (int mi = 0; mi < 4; ++mi)
                #pragma unroll
                for (int ni = 0; ni < 4; ++ni)
                    acc[mi][ni] = __builtin_amdgcn_mfma_f32_16x16x32_f16(af[mi], bfr[ni], acc[mi][ni], 0, 0, 0);
        }
        __syncthreads();
    }

    float s_bn[4], t_bn[4];
    #pragma unroll
    for (int ni = 0; ni < 4; ++ni) {
        int o = orow0 + wc * 64 + ni * 16 + (lane & 15);
        float g = pp.g[o], be = pp.be[o], mu = pp.mu[o], va = pp.va[o];
        float s = g / sqrtf(va + 1e-5f);
        s_bn[ni] = s; t_bn[ni] = be - mu * s;
    }
    #pragma unroll
    for (int mi = 0; mi < 4; ++mi)
        #pragma unroll
        for (int ni = 0; ni < 4; ++ni) {
            int o = orow0 + wc * 64 + ni * 16 + (lane & 15);
            int n = n0 + wr * 64 + mi * 16 + (lane >> 4) * 4;
            f32x4 vv;
            #pragma unroll
            for (int r = 0; r < 4; ++r)
                vv[r] = acc[mi][ni][r] * s_bn[ni] + t_bn[ni];
            *(f32x4*)(out + ((size_t)b * C_ + o) * N_ + n) = vv;
        }
}

extern "C" void kernel_launch(void* const* d_in, const int* in_sizes, int n_in,
                              void* d_out, int out_size, void* d_ws, size_t ws_size,
                              hipStream_t stream) {
    P5 pq { (const float*)d_in[1],  (const float*)d_in[2],  (const float*)d_in[3],
            (const float*)d_in[4],  (const float*)d_in[5] };
    P5 pk { (const float*)d_in[6],  (const float*)d_in[7],  (const float*)d_in[8],
            (const float*)d_in[9],  (const float*)d_in[10] };
    P5 pv { (const float*)d_in[11], (const float*)d_in[12], (const float*)d_in[13],
            (const float*)d_in[14], (const float*)d_in[15] };
    P5 pp { (const float*)d_in[16], (const float*)d_in[17], (const float*)d_in[18],
            (const float*)d_in[19], (const float*)d_in[20] };
    W4 w4 { pq.w, pk.w, pv.w, pp.w };

    char* ws = (char*)d_ws;
    const size_t S = (size_t)B_ * C_ * N_ * 2;          // 25165824 B per 16-bit tensor
    unsigned short* xst = (unsigned short*)ws;          // f16; aliased with a_s (disjoint lifetimes)
    unsigned short* qs  = (unsigned short*)(ws + S);
    unsigned short* ks  = (unsigned short*)(ws + 2 * S + 256);
    unsigned short* vs  = (unsigned short*)(ws + 3 * S + 512);
    float*          kvf = (float*)(ws + 4 * S + 768);                          // 589824 B
    unsigned short* hi  = (unsigned short*)(ws + 4 * S + 768 + 589824);        // 393216 B
    unsigned short* lo  = (unsigned short*)(ws + 4 * S + 768 + 589824 + 393216);
    unsigned short* wsp = (unsigned short*)(ws + 4 * S + 768 + 589824 + 2 * 393216); // 2359296 B
    unsigned short* as_ = xst;

    hipMemsetAsync(kvf, 0, 589824, stream);
    k_prep<<<2304, 256, 0, stream>>>(w4, wsp);
    k0_spike_T<<<dim3(64, 6, 8), 256, 0, stream>>>((const float*)d_in[0], xst);
    k1_qkv<<<2304, 256, 0, stream>>>(xst, wsp, pq, pk, pv, qs, ks, vs);
    k2_kv<<<1024, 256, 0, stream>>>(ks, vs, kvf);
    k2b_split<<<768, 256, 0, stream>>>(kvf, hi, lo);
    k3_attn<<<512, 256, 0, stream>>>(qs, hi, lo, as_);
    k4_pconv<<<768, 256, 0, stream>>>(as_, wsp, pp, (float*)d_out);
}

// Round 7
// 268.428 us; speedup vs baseline: 1.2302x; 1.0133x over previous
//
#include <hip/hip_runtime.h>
#include <stdint.h>

#define B_  8
#define C_  384
#define N_  4096
#define NH_ 8
#define HD_ 48
#define CB_ (C_*N_)
#define KS2 768   // 2 x 384 (scaled-f16 hi/lo split of f32 weights)

typedef __attribute__((ext_vector_type(8))) short short8;
typedef __attribute__((ext_vector_type(8))) _Float16 half8;
typedef __attribute__((ext_vector_type(4))) float f32x4;

// all inputs are float32 (reference dtypes)
struct P5 { const float *w, *g, *be, *mu, *va; };
struct W4 { const float *w0, *w1, *w2, *w3; };

__device__ __forceinline__ float b2f(unsigned short u) {
    union { unsigned int i; float f; } c; c.i = ((unsigned int)u) << 16; return c.f;
}
__device__ __forceinline__ unsigned short f2b(float f) {
    union { float f; unsigned int i; } c; c.f = f;
    return (unsigned short)((c.i + 0x7FFFu + ((c.i >> 16) & 1u)) >> 16);
}
__device__ __forceinline__ unsigned short f2h(float f) {   // f32 -> f16 bits (RTE); exact for quantized vals
    union { _Float16 h; unsigned short u; } c; c.h = (_Float16)f; return c.u;
}
__device__ __forceinline__ float spikef(float f) {
    f = fminf(fmaxf(f, 0.0f), 4.0f);
    return rintf(f) * 0.25f;   // round-half-even == np.round
}
__device__ __forceinline__ void async16(const void* g, void* l) {
    __builtin_amdgcn_global_load_lds((const __attribute__((address_space(1))) void*)g,
                                     (__attribute__((address_space(3))) void*)l, 16, 0, 0);
}

// ---------------- Kp: scaled-f16 2-way split of weights; also zeroes kvf ----------------
// wsp[mat][o][c']: c'<384: lo = f16((w-hi)*4096), c' in [384,768): hi = f16(w)
__global__ __launch_bounds__(256) void k_prep(W4 ws4, unsigned short* __restrict__ wsp,
                                              float* __restrict__ kvf) {
    int idx = blockIdx.x * 256 + threadIdx.x;          // 4*384*384 = 589824
    if (idx >= 589824) return;
    if (idx < 147456) kvf[idx] = 0.0f;                 // 64 bh * 2304 = 147456 floats exactly
    int mat = idx / 147456, rem = idx % 147456;
    int o = rem / 384, c = rem % 384;
    const float* W = (mat == 0) ? ws4.w0 : (mat == 1) ? ws4.w1 : (mat == 2) ? ws4.w2 : ws4.w3;
    float w = W[o * 384 + c];
    _Float16 hh = (fabsf(w) < 6.103515625e-05f) ? (_Float16)0 : (_Float16)w;  // keep hi normal (or 0)
    float r1 = w - (float)hh;                    // exact
    float s  = r1 * 4096.0f;                     // exact (pow2)
    union { _Float16 h; unsigned short u; } ch, cl;
    ch.h = hh; cl.h = (_Float16)s;
    unsigned short* row = wsp + (size_t)mat * 384 * KS2 + (size_t)o * KS2 + c;
    row[0] = cl.u; row[384] = ch.u;
}

// ---------------- K0: xs = spike(x) (f32 in), transposed to f16 [b][n][c] ----------------
__global__ __launch_bounds__(256) void k0_spike_T(const float* __restrict__ x,
                                                  unsigned short* __restrict__ xst) {
    int nt = blockIdx.x, ct = blockIdx.y, b = blockIdx.z;
    int t = threadIdx.x;
    __shared__ __attribute__((aligned(16))) unsigned short sm[64][68];
    int n0 = nt * 64, c0 = ct * 64;
    const float* xb = x + (size_t)b * CB_;
    #pragma unroll
    for (int i = 0; i < 4; ++i) {
        int c = (t >> 4) + 16 * i;
        int seg = t & 15;
        float4 d = *(const float4*)(xb + (size_t)(c0 + c) * N_ + n0 + seg * 4);
        unsigned short v[4];
        v[0] = f2h(spikef(d.x)); v[1] = f2h(spikef(d.y));
        v[2] = f2h(spikef(d.z)); v[3] = f2h(spikef(d.w));
        *(uint2*)&sm[c][seg * 4] = *(const uint2*)v;
    }
    __syncthreads();
    unsigned short* ob = xst + (size_t)b * CB_;
    #pragma unroll
    for (int i = 0; i < 2; ++i) {
        int flat = i * 256 + t;
        int n = flat >> 3, segc = flat & 7;
        unsigned short v[8];
        #pragma unroll
        for (int j = 0; j < 8; ++j) v[j] = sm[segc * 8 + j][n];
        *(uint4*)(ob + (size_t)(n0 + n) * C_ + c0 + segc * 8) = *(const uint4*)v;
    }
}

// ---------------- K1: fused q/k/v conv+BN+spike GEMM (2-pass scaled-f16), XCD-swizzled ----------------
__global__ __launch_bounds__(256) void k1_qkv(const unsigned short* __restrict__ xst,
                                              const unsigned short* __restrict__ wsp,
                                              P5 pq, P5 pk, P5 pv,
                                              unsigned short* __restrict__ qs,
                                              unsigned short* __restrict__ ks,
                                              unsigned short* __restrict__ vs) {
    int gid = blockIdx.x;
    int xcd = gid & 7, idx = gid >> 3;        // idx in [0,288)
    int pairSlot = idx / 9, mt = idx - pairSlot * 9;
    int p = xcd * 32 + pairSlot;              // [0,256): ntile-b pair
    int ntile = p >> 3, b = p & 7;
    int mat = mt / 3;
    int orow0 = (mt % 3) * 128;
    int n0 = ntile * 128;
    int t = threadIdx.x, lane = t & 63, wvv = t >> 6;
    int wr = wvv >> 1, wc = wvv & 1;

    __shared__ __attribute__((aligned(16))) short lds[17408]; // A | B (8192 shorts each); epilogue reuse
    P5 pp = (mat == 0) ? pq : (mat == 1 ? pk : pv);
    const unsigned short* abase = xst + (size_t)b * CB_;
    const unsigned short* wbase = wsp + (size_t)mat * 384 * KS2;

    f32x4 acc[4][4] = {};
    for (int kk = 0; kk < KS2; kk += 64) {
        if (kk == 384) {        // finished lo pass: scale partial sums by 2^-12
            #pragma unroll
            for (int mi = 0; mi < 4; ++mi)
                #pragma unroll
                for (int ni = 0; ni < 4; ++ni)
                    acc[mi][ni] = acc[mi][ni] * 0.000244140625f;
        }
        int ck = (kk >= 384) ? kk - 384 : kk;   // A repeats per pass (L2-hot after swizzle)
        #pragma unroll
        for (int j = 0; j < 4; ++j) {
            int row = wvv * 32 + j * 8 + (lane >> 3);
            int g = (lane & 7) ^ (row & 7);
            async16(abase + (size_t)(n0 + row) * C_ + ck + g * 8, lds + (wvv * 32 + j * 8) * 64);
        }
        #pragma unroll
        for (int j = 0; j < 4; ++j) {
            int row = wvv * 32 + j * 8 + (lane >> 3);
            int g = (lane & 7) ^ (row & 7);
            async16(wbase + (size_t)(orow0 + row) * KS2 + kk + g * 8, lds + 8192 + (wvv * 32 + j * 8) * 64);
        }
        __syncthreads();
        #pragma unroll
        for (int ksb = 0; ksb < 2; ++ksb) {
            half8 af[4], bfr[4];
            #pragma unroll
            for (int mi = 0; mi < 4; ++mi) {
                int row = wr * 64 + mi * 16 + (lane & 15);
                int s = (ksb * 4 + (lane >> 4)) ^ (row & 7);
                af[mi] = *(const half8*)&lds[row * 64 + s * 8];
            }
            #pragma unroll
            for (int ni = 0; ni < 4; ++ni) {
                int row = wc * 64 + ni * 16 + (lane & 15);
                int s = (ksb * 4 + (lane >> 4)) ^ (row & 7);
                bfr[ni] = *(const half8*)&lds[8192 + row * 64 + s * 8];
            }
            #pragma unroll
            for (int mi = 0; mi < 4; ++mi)
                #pragma unroll
                for (int ni = 0; ni < 4; ++ni)
                    acc[mi][ni] = __builtin_amdgcn_mfma_f32_16x16x32_f16(af[mi], bfr[ni], acc[mi][ni], 0, 0, 0);
        }
        __syncthreads();
    }

    float s_bn[4], t_bn[4];
    #pragma unroll
    for (int ni = 0; ni < 4; ++ni) {
        int o = orow0 + wc * 64 + ni * 16 + (lane & 15);
        float g = pp.g[o], be = pp.be[o], mu = pp.mu[o], va = pp.va[o];
        float s = g / sqrtf(va + 1e-5f);
        s_bn[ni] = s; t_bn[ni] = be - mu * s;
    }
    unsigned short* esm = (unsigned short*)lds;

    if (mat != 0) {  // k,v -> [b][c][n] (bf16 for K2/K3)
        #pragma unroll
        for (int mi = 0; mi < 4; ++mi)
            #pragma unroll
            for (int ni = 0; ni < 4; ++ni) {
                int ol = wc * 64 + ni * 16 + (lane & 15);
                int nb = wr * 64 + mi * 16 + (lane >> 4) * 4;
                unsigned short vv[4];
                #pragma unroll
                for (int r = 0; r < 4; ++r)
                    vv[r] = f2b(spikef(acc[mi][ni][r] * s_bn[ni] + t_bn[ni]));
                *(uint2*)&esm[ol * 136 + nb] = *(const uint2*)vv;
            }
        __syncthreads();
        unsigned short* dst = ((mat == 1) ? ks : vs) + (size_t)b * CB_;
        #pragma unroll
        for (int i = 0; i < 8; ++i) {
            int o = (t >> 4) + 16 * i;
            int seg = t & 15;
            uint4 d = *(const uint4*)&esm[o * 136 + seg * 8];
            *(uint4*)(dst + (size_t)(orow0 + o) * N_ + n0 + seg * 8) = d;
        }
    } else {        // q -> [b][n][c] (bf16 for K3)
        #pragma unroll
        for (int mi = 0; mi < 4; ++mi)
            #pragma unroll
            for (int ni = 0; ni < 4; ++ni) {
                int ol = wc * 64 + ni * 16 + (lane & 15);
                int nb = wr * 64 + mi * 16 + (lane >> 4) * 4;
                #pragma unroll
                for (int r = 0; r < 4; ++r)
                    esm[(nb + r) * 136 + ol] = f2b(spikef(acc[mi][ni][r] * s_bn[ni] + t_bn[ni]));
            }
        __syncthreads();
        #pragma unroll
        for (int i = 0; i < 8; ++i) {
            int n = (t >> 4) + 16 * i;
            int seg = t & 15;
            uint4 d = *(const uint4*)&esm[n * 136 + seg * 8];
            *(uint4*)(qs + ((size_t)b * N_ + n0 + n) * C_ + orow0 + seg * 8) = d;
        }
    }
}

// ---------------- K2: kv = k^T v per (b,h), split-K over 16 chunks ----------------
__global__ __launch_bounds__(256) void k2_kv(const unsigned short* __restrict__ ks,
                                             const unsigned short* __restrict__ vs,
                                             float* __restrict__ kvf) {
    int id = blockIdx.x;                 // 1024 = 64 bh * 16 chunks
    int b = id >> 7, h = (id >> 4) & 7, ck = id & 15;
    int t = threadIdx.x, lane = t & 63, w = t >> 6;
    const unsigned short* kb = ks + (size_t)b * CB_ + h * HD_ * N_;
    const unsigned short* vb = vs + (size_t)b * CB_ + h * HD_ * N_;
    int kbase = ck * 256 + w * 64;

    f32x4 acc[3][3] = {};
    #pragma unroll
    for (int kk = 0; kk < 64; kk += 32) {
        int n = kbase + kk + (lane >> 4) * 8;
        short8 af[3], bfr[3];
        #pragma unroll
        for (int di = 0; di < 3; ++di)
            af[di] = *(const short8*)(kb + (size_t)((lane & 15) + 16 * di) * N_ + n);
        #pragma unroll
        for (int ei = 0; ei < 3; ++ei)
            bfr[ei] = *(const short8*)(vb + (size_t)((lane & 15) + 16 * ei) * N_ + n);
        #pragma unroll
        for (int di = 0; di < 3; ++di)
            #pragma unroll
            for (int ei = 0; ei < 3; ++ei)
                acc[di][ei] = __builtin_amdgcn_mfma_f32_16x16x32_bf16(af[di], bfr[ei], acc[di][ei], 0, 0, 0);
    }
    __shared__ float red[4][48][48];
    #pragma unroll
    for (int di = 0; di < 3; ++di)
        #pragma unroll
        for (int ei = 0; ei < 3; ++ei) {
            int d0 = di * 16 + (lane >> 4) * 4;
            int e = ei * 16 + (lane & 15);
            #pragma unroll
            for (int r = 0; r < 4; ++r) red[w][d0 + r][e] = acc[di][ei][r];
        }
    __syncthreads();
    for (int i = t; i < 2304; i += 256) {
        int e = i / 48, d = i % 48;
        float sum = red[0][d][e] + red[1][d][e] + red[2][d][e] + red[3][d][e];
        atomicAdd(&kvf[(b * NH_ + h) * 2304 + e * 48 + d], sum);  // [e][d]; exact (1/16 multiples)
    }
}

// ---------------- K3: attn = q @ kv * s2, spike -> a_s f16 [b][n][c] ----------------
// 1024 blocks = 8 b * 64 nt * 2 head-groups. q tile staged in LDS (swizzled chunks);
// kv split f32->bf16 hi/lo on the fly in LDS (replaces k2b); output overwrites q region.
__global__ __launch_bounds__(256) void k3_attn(const unsigned short* __restrict__ qs,
                                               const float* __restrict__ kvf,
                                               unsigned short* __restrict__ as_) {
    int id = blockIdx.x;
    int hg = id & 1, nt = (id >> 1) & 63, b = id >> 7;
    int t = threadIdx.x, lane = t & 63, w = t >> 6;
    int nb0 = nt * 64;
    __shared__ __attribute__((aligned(16))) unsigned short ldsq[64 * 24 * 8]; // [row][24 chunks of 8] swizzled
    __shared__ __attribute__((aligned(16))) unsigned short ldsh[48 * 72];     // kv hi bf16, [e][72-pad d]
    __shared__ __attribute__((aligned(16))) unsigned short ldsl[48 * 72];     // kv lo bf16

    const unsigned short* qb = qs + ((size_t)b * N_ + nb0) * C_ + hg * 192;
    // stage q tile [64 n][192 c]: 1536 16-B chunks; slot sc holds source chunk sc^(row&7)
    #pragma unroll
    for (int i = 0; i < 6; ++i) {
        int g = (i * 4 + w) * 64;             // wave-uniform slot base
        int f = g + lane;
        int row = f / 24, sc = f % 24;
        int c = sc ^ (row & 7);
        async16(qb + (size_t)row * C_ + c * 8, ldsq + (size_t)g * 8);
    }
    const float* kvb = kvf + ((size_t)(b * NH_ + hg * 4)) * 2304;
    const float S2 = 0.28867513459481287f;    // f32(2/sqrt(48)) as in reference
    int quad = lane >> 4;
    int qrow = w * 16 + (lane & 15);

    for (int hl = 0; hl < 4; ++hl) {
        __syncthreads();                       // prev kv reads done (and drains q staging on first iter)
        const float* kvh = kvb + hl * 2304;
        for (int i = t; i < 48 * 64; i += 256) {
            int e = i >> 6, d = i & 63;
            unsigned short h16 = 0, l16 = 0;
            if (d < 48) {
                float v = kvh[e * 48 + d];
                h16 = f2b(v);
                l16 = f2b(v - b2f(h16));       // hi+lo == v exactly (1/16-granular fixed point)
            }
            ldsh[e * 72 + d] = h16;
            ldsl[e * 72 + d] = l16;
        }
        __syncthreads();

        f32x4 acc[3] = {};
        #pragma unroll
        for (int ksb = 0; ksb < 2; ++ksb) {
            int c = hl * 6 + ksb * 4 + quad;   // q chunk; >23 only where B pad is zero
            int cc = c > 23 ? 23 : c;          // clamp in-bounds (finite; product zeroed by pad)
            int slot = cc ^ (qrow & 7);
            short8 a = *(const short8*)&ldsq[(qrow * 24 + slot) * 8];
            #pragma unroll
            for (int ei = 0; ei < 3; ++ei) {
                int e = ei * 16 + (lane & 15);
                short8 bh = *(const short8*)&ldsh[e * 72 + ksb * 32 + quad * 8];
                short8 bl = *(const short8*)&ldsl[e * 72 + ksb * 32 + quad * 8];
                acc[ei] = __builtin_amdgcn_mfma_f32_16x16x32_bf16(a, bh, acc[ei], 0, 0, 0);
                acc[ei] = __builtin_amdgcn_mfma_f32_16x16x32_bf16(a, bl, acc[ei], 0, 0, 0);
            }
        }
        // spike -> write back into own rows' q region (cols hl*48..+48), f16 for K4
        #pragma unroll
        for (int ei = 0; ei < 3; ++ei) {
            int col = hl * 48 + ei * 16 + (lane & 15);
            int ch = col >> 3, j = col & 7;
            #pragma unroll
            for (int r = 0; r < 4; ++r) {
                int row = w * 16 + quad * 4 + r;
                ldsq[(row * 24 + (ch ^ (row & 7))) * 8 + j] = f2h(spikef(acc[ei][r] * S2));
            }
        }
    }
    __syncthreads();
    unsigned short* ob = as_ + ((size_t)b * N_ + nb0) * C_ + hg * 192;
    #pragma unroll
    for (int i = 0; i < 6; ++i) {
        int f = i * 256 + t;
        int row = f / 24, sc = f % 24;
        int slot = sc ^ (row & 7);
        uint4 d = *(const uint4*)&ldsq[(row * 24 + slot) * 8];
        *(uint4*)(ob + (size_t)row * C_ + sc * 8) = d;
    }
}

// ---------------- K4: out = BN(P @ a_s) -> f32 [b][c][n], LDS-staged coalesced stores ----------------
__global__ __launch_bounds__(256) void k4_pconv(const unsigned short* __restrict__ as_,
                                                const unsigned short* __restrict__ wsp,
                                                P5 pp,
                                                float* __restrict__ out) {
    int gid = blockIdx.x;                      // 768 = 8 xcd * 96
    int xcd = gid & 7, idx = gid >> 3;         // idx in [0,96)
    int pairSlot = idx / 3, mt = idx - pairSlot * 3;
    int p = xcd * 32 + pairSlot;               // [0,256)
    int ntile = p >> 3, b = p & 7;
    int orow0 = mt * 128;
    int n0 = ntile * 128;
    int t = threadIdx.x, lane = t & 63, wvv = t >> 6;
    int wr = wvv >> 1, wc = wvv & 1;

    __shared__ __attribute__((aligned(16))) char ldsb[33792]; // staging 32 KB | f32 tile 64x132
    short* lds = (short*)ldsb;
    const unsigned short* abase = as_ + (size_t)b * CB_;
    const unsigned short* wbase = wsp + (size_t)3 * 384 * KS2;   // p-matrix split

    f32x4 acc[4][4] = {};
    for (int kk = 0; kk < KS2; kk += 64) {
        if (kk == 384) {
            #pragma unroll
            for (int mi = 0; mi < 4; ++mi)
                #pragma unroll
                for (int ni = 0; ni < 4; ++ni)
                    acc[mi][ni] = acc[mi][ni] * 0.000244140625f;
        }
        int ck = (kk >= 384) ? kk - 384 : kk;
        #pragma unroll
        for (int j = 0; j < 4; ++j) {
            int row = wvv * 32 + j * 8 + (lane >> 3);
            int g = (lane & 7) ^ (row & 7);
            async16(abase + (size_t)(n0 + row) * C_ + ck + g * 8, lds + (wvv * 32 + j * 8) * 64);
        }
        #pragma unroll
        for (int j = 0; j < 4; ++j) {
            int row = wvv * 32 + j * 8 + (lane >> 3);
            int g = (lane & 7) ^ (row & 7);
            async16(wbase + (size_t)(orow0 + row) * KS2 + kk + g * 8, lds + 8192 + (wvv * 32 + j * 8) * 64);
        }
        __syncthreads();
        #pragma unroll
        for (int ksb = 0; ksb < 2; ++ksb) {
            half8 af[4], bfr[4];
            #pragma unroll
            for (int mi = 0; mi < 4; ++mi) {
                int row = wr * 64 + mi * 16 + (lane & 15);
                int s = (ksb * 4 + (lane >> 4)) ^ (row & 7);
                af[mi] = *(const half8*)&lds[row * 64 + s * 8];
            }
            #pragma unroll
            for (int ni = 0; ni < 4; ++ni) {
                int row = wc * 64 + ni * 16 + (lane & 15);
                int s = (ksb * 4 + (lane >> 4)) ^ (row & 7);
                bfr[ni] = *(const half8*)&lds[8192 + row * 64 + s * 8];
            }
            #pragma unroll
            for (int mi = 0; mi < 4; ++mi)
                #pragma unroll
                for (int ni = 0; ni < 4; ++ni)
                    acc[mi][ni] = __builtin_amdgcn_mfma_f32_16x16x32_f16(af[mi], bfr[ni], acc[mi][ni], 0, 0, 0);
        }
        __syncthreads();
    }

    float s_bn[4], t_bn[4];
    #pragma unroll
    for (int ni = 0; ni < 4; ++ni) {
        int o = orow0 + wc * 64 + ni * 16 + (lane & 15);
        float g = pp.g[o], be = pp.be[o], mu = pp.mu[o], va = pp.va[o];
        float s = g / sqrtf(va + 1e-5f);
        s_bn[ni] = s; t_bn[ni] = be - mu * s;
    }
    // two o-halves through a padded f32 LDS tile [64 o][132 n] -> 512-B coalesced runs
    float* fsm = (float*)ldsb;
    for (int half = 0; half < 2; ++half) {
        __syncthreads();
        if (wc == half) {
            #pragma unroll
            for (int mi = 0; mi < 4; ++mi)
                #pragma unroll
                for (int ni = 0; ni < 4; ++ni) {
                    int ol = ni * 16 + (lane & 15);
                    int nl = wr * 64 + mi * 16 + (lane >> 4) * 4;
                    f32x4 vv;
                    #pragma unroll
                    for (int r = 0; r < 4; ++r)
                        vv[r] = acc[mi][ni][r] * s_bn[ni] + t_bn[ni];
                    *(f32x4*)&fsm[ol * 132 + nl] = vv;
                }
        }
        __syncthreads();
        #pragma unroll
        for (int i = 0; i < 8; ++i) {
            int f = i * 256 + t;
            int o = f >> 5, slot = f & 31;
            f32x4 vv = *(const f32x4*)&fsm[o * 132 + slot * 4];
            *(f32x4*)(out + ((size_t)b * C_ + orow0 + half * 64 + o) * N_ + n0 + slot * 4) = vv;
        }
    }
}

extern "C" void kernel_launch(void* const* d_in, const int* in_sizes, int n_in,
                              void* d_out, int out_size, void* d_ws, size_t ws_size,
                              hipStream_t stream) {
    P5 pq { (const float*)d_in[1],  (const float*)d_in[2],  (const float*)d_in[3],
            (const float*)d_in[4],  (const float*)d_in[5] };
    P5 pk { (const float*)d_in[6],  (const float*)d_in[7],  (const float*)d_in[8],
            (const float*)d_in[9],  (const float*)d_in[10] };
    P5 pv { (const float*)d_in[11], (const float*)d_in[12], (const float*)d_in[13],
            (const float*)d_in[14], (const float*)d_in[15] };
    P5 pp { (const float*)d_in[16], (const float*)d_in[17], (const float*)d_in[18],
            (const float*)d_in[19], (const float*)d_in[20] };
    W4 w4 { pq.w, pk.w, pv.w, pp.w };

    char* ws = (char*)d_ws;
    const size_t S = (size_t)B_ * C_ * N_ * 2;          // 25165824 B per 16-bit tensor
    unsigned short* xst = (unsigned short*)ws;          // f16; aliased with a_s (disjoint lifetimes)
    unsigned short* qs  = (unsigned short*)(ws + S);
    unsigned short* ks  = (unsigned short*)(ws + 2 * S + 256);
    unsigned short* vs  = (unsigned short*)(ws + 3 * S + 512);
    float*          kvf = (float*)(ws + 4 * S + 768);                          // 589824 B
    unsigned short* wsp = (unsigned short*)(ws + 4 * S + 768 + 589824);        // 2359296 B
    unsigned short* as_ = xst;

    k_prep<<<2304, 256, 0, stream>>>(w4, wsp, kvf);
    k0_spike_T<<<dim3(64, 6, 8), 256, 0, stream>>>((const float*)d_in[0], xst);
    k1_qkv<<<2304, 256, 0, stream>>>(xst, wsp, pq, pk, pv, qs, ks, vs);
    k2_kv<<<1024, 256, 0, stream>>>(ks, vs, kvf);
    k3_attn<<<1024, 256, 0, stream>>>(qs, kvf, as_);
    k4_pconv<<<768, 256, 0, stream>>>(as_, wsp, pp, (float*)d_out);
}